// Round 2
// baseline (2695.521 us; speedup 1.0000x reference)
//
#include <hip/hip_runtime.h>

#define TPB 256

// ---- zero counts ----
__global__ void k_zero(int* p, int n) {
    int i = blockIdx.x * blockDim.x + threadIdx.x;
    if (i < n) p[i] = 0;
}

// ---- histogram of dst ----
__global__ void k_hist(const int* __restrict__ ed, int* cnt, int E) {
    int i = blockIdx.x * blockDim.x + threadIdx.x;
    if (i < E) atomicAdd(&cnt[ed[i]], 1);
}

// ---- scan pass 1: per-block exclusive scan of 1024 elements, block totals out ----
__global__ void k_scan1(int* data, int* bsums, int n) {
    __shared__ int lds[256];
    int t = threadIdx.x;
    int base = blockIdx.x * 1024 + t * 4;
    int c[4];
#pragma unroll
    for (int k = 0; k < 4; k++) {
        int i = base + k;
        c[k] = (i < n) ? data[i] : 0;
    }
    int sum = c[0] + c[1] + c[2] + c[3];
    lds[t] = sum;
    __syncthreads();
    // Hillis-Steele inclusive scan over 256 thread sums
    for (int off = 1; off < 256; off <<= 1) {
        int v = (t >= off) ? lds[t - off] : 0;
        __syncthreads();
        lds[t] += v;
        __syncthreads();
    }
    int excl = lds[t] - sum;
    int run = excl;
#pragma unroll
    for (int k = 0; k < 4; k++) {
        int i = base + k;
        if (i < n) data[i] = run;
        run += c[k];
    }
    if (t == 255) bsums[blockIdx.x] = lds[255];
}

// ---- scan pass 2: single block scans block sums (nb <= 512) ----
__global__ void k_scan2(int* bsums, int nb) {
    __shared__ int lds[512];
    int t = threadIdx.x;
    int v = (t < nb) ? bsums[t] : 0;
    lds[t] = v;
    __syncthreads();
    for (int off = 1; off < 512; off <<= 1) {
        int u = (t >= off) ? lds[t - off] : 0;
        __syncthreads();
        lds[t] += u;
        __syncthreads();
    }
    if (t < nb) bsums[t] = lds[t] - v;  // exclusive
}

// ---- scan pass 3: add block offsets ----
__global__ void k_scan3(int* data, const int* __restrict__ bsums, int n) {
    int i = blockIdx.x * blockDim.x + threadIdx.x;
    if (i < n) data[i] += bsums[i >> 10];
}

// ---- dis = rsqrt(deg+1), from pre-fill row_start differences ----
__global__ void k_dis(const int* __restrict__ row_start, float* __restrict__ dis, int n, int E) {
    int v = blockIdx.x * blockDim.x + threadIdx.x;
    if (v >= n) return;
    int b = row_start[v];
    int e = (v == n - 1) ? E : row_start[v + 1];
    dis[v] = rsqrtf((float)(e - b + 1));
}

// ---- fill CSR: consumes row_start (becomes row_end) ----
__global__ void k_fill(const int* __restrict__ es, const int* __restrict__ ed,
                       int* cursor, int* __restrict__ src_sorted, int E) {
    int i = blockIdx.x * blockDim.x + threadIdx.x;
    if (i >= E) return;
    int s = es[i], d = ed[i];
    int pos = atomicAdd(&cursor[d], 1);
    src_sorted[pos] = s;
}

// ---- layer1+layer2-transform fused: 4 lanes per node ----
// aggx = sum x[u]*dis[u] (incl self); h1 = relu(dis*(aggx@W1)+b1); h2s = (h1@W2)*dis
__global__ void k_agg1(const float* __restrict__ x, const float* __restrict__ dis,
                       const int* __restrict__ row_end, const int* __restrict__ src_sorted,
                       const float* __restrict__ W1, const float* __restrict__ b1,
                       const float* __restrict__ W2, float* __restrict__ h2s, int n) {
    __shared__ float sW1[192];
    __shared__ float sb1[16];
    __shared__ float sW2[128];
    int t = threadIdx.x;
    if (t < 192) sW1[t] = W1[t];
    if (t < 16) sb1[t] = b1[t];
    if (t < 128) sW2[t] = W2[t];
    __syncthreads();

    int v = blockIdx.x * 64 + (t >> 2);
    if (v >= n) return;
    int l = t & 3;

    int begin = (v == 0) ? 0 : row_end[v - 1];
    int end = row_end[v];
    float dv = dis[v];

    // self-loop seed: x[v]*dis[v], features [3l, 3l+3)
    const float* xv = x + (size_t)v * 12 + l * 3;
    float a0 = xv[0] * dv, a1 = xv[1] * dv, a2 = xv[2] * dv;

    for (int j = begin; j < end; ++j) {
        int s = src_sorted[j];
        float ds = dis[s];
        const float* xs = x + (size_t)s * 12 + l * 3;
        a0 = fmaf(xs[0], ds, a0);
        a1 = fmaf(xs[1], ds, a1);
        a2 = fmaf(xs[2], ds, a2);
    }

    // exchange: every lane gets full aggx[12]
    int baseLane = (t & 63) & ~3;
    float aggx[12];
#pragma unroll
    for (int k = 0; k < 12; k++) {
        float src = (k % 3 == 0) ? a0 : ((k % 3 == 1) ? a1 : a2);
        aggx[k] = __shfl(src, baseLane + k / 3, 64);
    }

    float h1[16];
#pragma unroll
    for (int jj = 0; jj < 16; jj++) {
        float acc = 0.f;
#pragma unroll
        for (int k = 0; k < 12; k++) acc = fmaf(aggx[k], sW1[k * 16 + jj], acc);
        h1[jj] = fmaxf(fmaf(dv, acc, sb1[jj]), 0.f);
    }

#pragma unroll
    for (int oo = 0; oo < 2; oo++) {
        int o = 2 * l + oo;
        float acc = 0.f;
#pragma unroll
        for (int jj = 0; jj < 16; jj++) acc = fmaf(h1[jj], sW2[jj * 8 + o], acc);
        h2s[(size_t)v * 8 + o] = acc * dv;
    }
}

// ---- layer2 aggregation + epilogue: 4 lanes per node, 2 feats per lane ----
__global__ void k_agg2(const float* __restrict__ h2s, const float* __restrict__ dis,
                       const int* __restrict__ row_end, const int* __restrict__ src_sorted,
                       const float* __restrict__ b2, float* __restrict__ out, int n) {
    int t = threadIdx.x;
    int v = blockIdx.x * 64 + (t >> 2);
    if (v >= n) return;
    int l = t & 3;

    int begin = (v == 0) ? 0 : row_end[v - 1];
    int end = row_end[v];

    // self-loop seed (dis[v] already folded into h2s[v])
    float acc0 = h2s[(size_t)v * 8 + 2 * l];
    float acc1 = h2s[(size_t)v * 8 + 2 * l + 1];

    for (int j = begin; j < end; ++j) {
        int s = src_sorted[j];
        const float2 q = *(const float2*)(h2s + (size_t)s * 8 + 2 * l);
        acc0 += q.x;
        acc1 += q.y;
    }

    float dv = dis[v];
    out[(size_t)v * 8 + 2 * l]     = fmaf(dv, acc0, b2[2 * l]);
    out[(size_t)v * 8 + 2 * l + 1] = fmaf(dv, acc1, b2[2 * l + 1]);
}

extern "C" void kernel_launch(void* const* d_in, const int* in_sizes, int n_in,
                              void* d_out, int out_size, void* d_ws, size_t ws_size,
                              hipStream_t stream) {
    const float* x  = (const float*)d_in[0];
    const int*   ei = (const int*)d_in[1];
    const float* W1 = (const float*)d_in[2];
    const float* b1 = (const float*)d_in[3];
    const float* W2 = (const float*)d_in[4];
    const float* b2 = (const float*)d_in[5];
    float* out = (float*)d_out;

    int n = in_sizes[0] / 12;
    int E = in_sizes[1] / 2;
    const int* es = ei;       // edge_index[0] = src
    const int* ed = ei + E;   // edge_index[1] = dst

    // workspace layout (ints/floats, all 4B):
    // row_end   : n+2 ints   (counts -> row_start -> consumed to row_end)
    // dis       : n floats
    // h2s       : 8n floats  (8-byte aligned: offset (2n+2)*4)
    // src_sorted: E ints
    // bsums     : 512 ints
    int* row_end = (int*)d_ws;
    float* dis = (float*)d_ws + (size_t)(n + 2);
    float* h2s = dis + n;
    int* src_sorted = (int*)(h2s + (size_t)8 * n);
    int* bsums = src_sorted + E;

    int nb_n = (n + TPB - 1) / TPB;
    int nb_e = (E + TPB - 1) / TPB;
    int nb_scan = (n + 1023) / 1024;

    k_zero<<<nb_n, TPB, 0, stream>>>(row_end, n);
    k_hist<<<nb_e, TPB, 0, stream>>>(ed, row_end, E);
    k_scan1<<<nb_scan, TPB, 0, stream>>>(row_end, bsums, n);
    k_scan2<<<1, 512, 0, stream>>>(bsums, nb_scan);
    k_scan3<<<nb_n, TPB, 0, stream>>>(row_end, bsums, n);
    k_dis<<<nb_n, TPB, 0, stream>>>(row_end, dis, n, E);
    k_fill<<<nb_e, TPB, 0, stream>>>(es, ed, row_end, src_sorted, E);

    long long tg = (long long)n * 4;
    int nb_g = (int)((tg + TPB - 1) / TPB);
    k_agg1<<<nb_g, TPB, 0, stream>>>(x, dis, row_end, src_sorted, W1, b1, W2, h2s, n);
    k_agg2<<<nb_g, TPB, 0, stream>>>(h2s, dis, row_end, src_sorted, b2, out, n);
}

// Round 3
// 2538.944 us; speedup vs baseline: 1.0617x; 1.0617x over previous
//
#include <hip/hip_runtime.h>

#define TPB 512
#define CH  32768   // edges per count/scatter block
#define NPB 512     // nodes per bucket (bucket = dst >> 9)

// ---- zero bucket counts ----
__global__ void k_zero(int* p, int n) {
    int i = blockIdx.x * blockDim.x + threadIdx.x;
    if (i < n) p[i] = 0;
}

// ---- per-chunk LDS histogram of dst-buckets, flush to global ----
__global__ void k_count(const int* __restrict__ ed, int* gcnt, int E, int B) {
    __shared__ int cnt[1024];
    int t = threadIdx.x;
    for (int i = t; i < B; i += TPB) cnt[i] = 0;
    __syncthreads();
    int start = blockIdx.x * CH;
    int end = min(E, start + CH);
    for (int i = start + t; i < end; i += TPB)
        atomicAdd(&cnt[ed[i] >> 9], 1);
    __syncthreads();
    for (int b = t; b < B; b += TPB) {
        int c = cnt[b];
        if (c) atomicAdd(&gcnt[b], c);
    }
}

// ---- single-block exclusive scan over B<=1024 bucket counts ----
__global__ void k_scan(const int* __restrict__ gcnt, int* __restrict__ bbase,
                       int* __restrict__ bcur, int B, int E) {
    __shared__ int lds[1024];
    int t = threadIdx.x;
    int v = (t < B) ? gcnt[t] : 0;
    lds[t] = v;
    __syncthreads();
    for (int off = 1; off < 1024; off <<= 1) {
        int u = (t >= off) ? lds[t - off] : 0;
        __syncthreads();
        lds[t] += u;
        __syncthreads();
    }
    if (t < B) {
        int excl = lds[t] - v;
        bbase[t] = excl;
        bcur[t] = excl;
    }
    if (t == 0) bbase[B] = E;
}

// ---- bin edges by bucket: LDS hist -> one global cursor reservation per (block,bucket) ----
__global__ void k_scatter(const int* __restrict__ es, const int* __restrict__ ed,
                          int* bcur, int* __restrict__ bsrc, unsigned short* __restrict__ bdlo,
                          int E, int B) {
    __shared__ int cnt[1024];
    __shared__ int cur[1024];
    __shared__ int gbase[1024];
    int t = threadIdx.x;
    for (int i = t; i < B; i += TPB) { cnt[i] = 0; cur[i] = 0; }
    __syncthreads();
    int start = blockIdx.x * CH;
    int end = min(E, start + CH);
    for (int i = start + t; i < end; i += TPB)
        atomicAdd(&cnt[ed[i] >> 9], 1);
    __syncthreads();
    for (int b = t; b < B; b += TPB) {
        int c = cnt[b];
        gbase[b] = c ? atomicAdd(&bcur[b], c) : 0;
    }
    __syncthreads();
    for (int i = start + t; i < end; i += TPB) {
        int d = ed[i];
        int b = d >> 9;
        int r = atomicAdd(&cur[b], 1);
        int pos = gbase[b] + r;
        bsrc[pos] = es[i];
        bdlo[pos] = (unsigned short)(d & (NPB - 1));
    }
}

// ---- per-bucket degree via LDS hist; dis = rsqrt(deg+1); xs = x * dis ----
__global__ void k_prep(const float* __restrict__ x, const int* __restrict__ bbase,
                       const unsigned short* __restrict__ bdlo,
                       float* __restrict__ dis, float* __restrict__ xs, int n) {
    __shared__ int cnt[NPB];
    int t = threadIdx.x;
    int b = blockIdx.x;
    cnt[t] = 0;
    __syncthreads();
    int e0 = bbase[b], e1 = bbase[b + 1];
    for (int e = e0 + t; e < e1; e += TPB)
        atomicAdd(&cnt[bdlo[e]], 1);
    __syncthreads();
    int v = (b << 9) + t;
    if (v < n) {
        float d = rsqrtf((float)(cnt[t] + 1));
        dis[v] = d;
        const float4* xp = (const float4*)(x + (size_t)v * 12);
        float4 a = xp[0], q = xp[1], c = xp[2];
        float4* op = (float4*)(xs + (size_t)v * 12);
        op[0] = make_float4(a.x * d, a.y * d, a.z * d, a.w * d);
        op[1] = make_float4(q.x * d, q.y * d, q.z * d, q.w * d);
        op[2] = make_float4(c.x * d, c.y * d, c.z * d, c.w * d);
    }
}

// ---- layer1 aggregate in LDS + fused matmuls: h2s = (relu(dis*(agg@W1)+b1) @ W2) * dis ----
__global__ void k_agg1(const float* __restrict__ xs, const float* __restrict__ dis,
                       const int* __restrict__ bbase, const int* __restrict__ bsrc,
                       const unsigned short* __restrict__ bdlo,
                       const float* __restrict__ W1, const float* __restrict__ b1,
                       const float* __restrict__ W2,
                       float* __restrict__ h2s, int n) {
    __shared__ float acc[NPB * 12];
    __shared__ float sW1[192], sb1[16], sW2[128];
    int t = threadIdx.x;
    int b = blockIdx.x;
    if (t < 192) sW1[t] = W1[t];
    else if (t >= 256 && t < 384) sW2[t - 256] = W2[t - 256];
    else if (t >= 448 && t < 464) sb1[t - 448] = b1[t - 448];
    int base = b << 9;
    int nn = min(NPB, n - base);
    if (t < nn) {
        const float* xp = xs + (size_t)(base + t) * 12;
#pragma unroll
        for (int k = 0; k < 12; k++) acc[t * 12 + k] = xp[k];  // self-loop seed
    }
    __syncthreads();
    int e0 = bbase[b], e1 = bbase[b + 1];
    for (int e = e0 + t; e < e1; e += TPB) {
        int s = bsrc[e];
        int r = bdlo[e];
        const float4* p = (const float4*)(xs + (size_t)s * 12);
        float4 a = p[0], q = p[1], c = p[2];
        float* ar = acc + r * 12;
        atomicAdd(ar + 0, a.x);  atomicAdd(ar + 1, a.y);  atomicAdd(ar + 2, a.z);  atomicAdd(ar + 3, a.w);
        atomicAdd(ar + 4, q.x);  atomicAdd(ar + 5, q.y);  atomicAdd(ar + 6, q.z);  atomicAdd(ar + 7, q.w);
        atomicAdd(ar + 8, c.x);  atomicAdd(ar + 9, c.y);  atomicAdd(ar + 10, c.z); atomicAdd(ar + 11, c.w);
    }
    __syncthreads();
    if (t < nn) {
        int v = base + t;
        float dv = dis[v];
        float aggx[12];
#pragma unroll
        for (int k = 0; k < 12; k++) aggx[k] = acc[t * 12 + k];
        float h1[16];
#pragma unroll
        for (int j = 0; j < 16; j++) {
            float s = 0.f;
#pragma unroll
            for (int k = 0; k < 12; k++) s = fmaf(aggx[k], sW1[k * 16 + j], s);
            h1[j] = fmaxf(fmaf(dv, s, sb1[j]), 0.f);
        }
        float o[8];
#pragma unroll
        for (int j = 0; j < 8; j++) {
            float s = 0.f;
#pragma unroll
            for (int k = 0; k < 16; k++) s = fmaf(h1[k], sW2[k * 8 + j], s);
            o[j] = s * dv;
        }
        float4* hp = (float4*)(h2s + (size_t)v * 8);
        hp[0] = make_float4(o[0], o[1], o[2], o[3]);
        hp[1] = make_float4(o[4], o[5], o[6], o[7]);
    }
}

// ---- layer2 aggregate in LDS + epilogue ----
__global__ void k_agg2(const float* __restrict__ h2s, const float* __restrict__ dis,
                       const int* __restrict__ bbase, const int* __restrict__ bsrc,
                       const unsigned short* __restrict__ bdlo,
                       const float* __restrict__ b2, float* __restrict__ out, int n) {
    __shared__ float acc[NPB * 8];
    __shared__ float sb2[8];
    int t = threadIdx.x;
    int b = blockIdx.x;
    if (t < 8) sb2[t] = b2[t];
    int base = b << 9;
    int nn = min(NPB, n - base);
    if (t < nn) {
        const float4* hp = (const float4*)(h2s + (size_t)(base + t) * 8);
        float4 a = hp[0], c = hp[1];
        float* ar = acc + t * 8;
        ar[0] = a.x; ar[1] = a.y; ar[2] = a.z; ar[3] = a.w;
        ar[4] = c.x; ar[5] = c.y; ar[6] = c.z; ar[7] = c.w;
    }
    __syncthreads();
    int e0 = bbase[b], e1 = bbase[b + 1];
    for (int e = e0 + t; e < e1; e += TPB) {
        int s = bsrc[e];
        int r = bdlo[e];
        const float4* p = (const float4*)(h2s + (size_t)s * 8);
        float4 a = p[0], c = p[1];
        float* ar = acc + r * 8;
        atomicAdd(ar + 0, a.x); atomicAdd(ar + 1, a.y); atomicAdd(ar + 2, a.z); atomicAdd(ar + 3, a.w);
        atomicAdd(ar + 4, c.x); atomicAdd(ar + 5, c.y); atomicAdd(ar + 6, c.z); atomicAdd(ar + 7, c.w);
    }
    __syncthreads();
    if (t < nn) {
        int v = base + t;
        float dv = dis[v];
        float* ar = acc + t * 8;
        float4* op = (float4*)(out + (size_t)v * 8);
        op[0] = make_float4(fmaf(dv, ar[0], sb2[0]), fmaf(dv, ar[1], sb2[1]),
                            fmaf(dv, ar[2], sb2[2]), fmaf(dv, ar[3], sb2[3]));
        op[1] = make_float4(fmaf(dv, ar[4], sb2[4]), fmaf(dv, ar[5], sb2[5]),
                            fmaf(dv, ar[6], sb2[6]), fmaf(dv, ar[7], sb2[7]));
    }
}

extern "C" void kernel_launch(void* const* d_in, const int* in_sizes, int n_in,
                              void* d_out, int out_size, void* d_ws, size_t ws_size,
                              hipStream_t stream) {
    const float* x  = (const float*)d_in[0];
    const int*   ei = (const int*)d_in[1];
    const float* W1 = (const float*)d_in[2];
    const float* b1 = (const float*)d_in[3];
    const float* W2 = (const float*)d_in[4];
    const float* b2 = (const float*)d_in[5];
    float* out = (float*)d_out;

    int n = in_sizes[0] / 12;
    int E = in_sizes[1] / 2;
    const int* es = ei;       // edge_index[0] = src
    const int* ed = ei + E;   // edge_index[1] = dst

    int B = (n + NPB - 1) >> 9;  // buckets (977 for n=500K, <=1024)

    // workspace layout (bytes):
    // gcnt @0 (16KB) | bbase @16KB (16KB) | bcur @32KB (16KB) | dis @48KB (4n)
    // xs @48KB+4n (48n) | h2s (32n) | bsrc (4E) | bdlo (2E)   total ~132 MiB
    char* wp = (char*)d_ws;
    int* gcnt  = (int*)wp;
    int* bbase = (int*)(wp + (16 << 10));
    int* bcur  = (int*)(wp + (32 << 10));
    float* dis = (float*)(wp + (48 << 10));
    float* xs  = dis + n;
    float* h2s = xs + (size_t)12 * n;
    int* bsrc  = (int*)(h2s + (size_t)8 * n);
    unsigned short* bdlo = (unsigned short*)(bsrc + E);

    int nchunks = (E + CH - 1) / CH;

    k_zero<<<(B + 255) / 256, 256, 0, stream>>>(gcnt, B);
    k_count<<<nchunks, TPB, 0, stream>>>(ed, gcnt, E, B);
    k_scan<<<1, 1024, 0, stream>>>(gcnt, bbase, bcur, B, E);
    k_scatter<<<nchunks, TPB, 0, stream>>>(es, ed, bcur, bsrc, bdlo, E, B);
    k_prep<<<B, TPB, 0, stream>>>(x, bbase, bdlo, dis, xs, n);
    k_agg1<<<B, TPB, 0, stream>>>(xs, dis, bbase, bsrc, bdlo, W1, b1, W2, h2s, n);
    k_agg2<<<B, TPB, 0, stream>>>(h2s, dis, bbase, bsrc, bdlo, b2, out, n);
}

// Round 4
// 2182.280 us; speedup vs baseline: 1.2352x; 1.1634x over previous
//
#include <hip/hip_runtime.h>

#define TPB 512
#define CH  32768       // edges per count/scatter block
#define NPB 512         // nodes per dst-bucket (bucket = dst >> 9)
#define SCH_SHIFT 16    // src chunk = src >> 16  (64K nodes = 3MB of xs, fits XCD L2)
#define NBIN 8192       // max (buckets * 8) bins

// ---- zero bin counts ----
__global__ void k_zero(int* p, int n) {
    int i = blockIdx.x * blockDim.x + threadIdx.x;
    if (i < n) p[i] = 0;
}

// ---- per-chunk LDS histogram of (dst_bucket, src_chunk) bins ----
__global__ void k_count(const int* __restrict__ es, const int* __restrict__ ed,
                        int* gcnt, int E, int B2) {
    __shared__ int cnt[NBIN];
    int t = threadIdx.x;
    for (int i = t; i < B2; i += TPB) cnt[i] = 0;
    __syncthreads();
    int start = blockIdx.x * CH;
    int end = min(E, start + CH);
    for (int i = start + t; i < end; i += TPB) {
        int b = ((ed[i] >> 9) << 3) | (es[i] >> SCH_SHIFT);
        atomicAdd(&cnt[b], 1);
    }
    __syncthreads();
    for (int b = t; b < B2; b += TPB) {
        int c = cnt[b];
        if (c) atomicAdd(&gcnt[b], c);
    }
}

// ---- single-block exclusive scan over B2 <= 8192 bins (1024 thr x 8) ----
__global__ void k_scan(const int* __restrict__ gcnt, int* __restrict__ bbase,
                       int* __restrict__ bcur, int B2, int E) {
    __shared__ int lds[1024];
    int t = threadIdx.x;
    int c[8];
    int sum = 0;
#pragma unroll
    for (int k = 0; k < 8; k++) {
        int i = t * 8 + k;
        c[k] = (i < B2) ? gcnt[i] : 0;
        sum += c[k];
    }
    lds[t] = sum;
    __syncthreads();
    for (int off = 1; off < 1024; off <<= 1) {
        int u = (t >= off) ? lds[t - off] : 0;
        __syncthreads();
        lds[t] += u;
        __syncthreads();
    }
    int run = lds[t] - sum;  // exclusive
#pragma unroll
    for (int k = 0; k < 8; k++) {
        int i = t * 8 + k;
        if (i < B2) { bbase[i] = run; bcur[i] = run; }
        run += c[k];
    }
    if (t == 0) bbase[B2] = E;
}

// ---- bin edges: LDS hist -> one cursor reservation per (block,bin); packed payload ----
__global__ void k_scatter(const int* __restrict__ es, const int* __restrict__ ed,
                          int* bcur, int* __restrict__ epk, int E, int B2) {
    __shared__ int cnt[NBIN];
    __shared__ int gbase[NBIN];
    int t = threadIdx.x;
    for (int i = t; i < B2; i += TPB) cnt[i] = 0;
    __syncthreads();
    int start = blockIdx.x * CH;
    int end = min(E, start + CH);
    for (int i = start + t; i < end; i += TPB) {
        int b = ((ed[i] >> 9) << 3) | (es[i] >> SCH_SHIFT);
        atomicAdd(&cnt[b], 1);
    }
    __syncthreads();
    for (int b = t; b < B2; b += TPB) {
        int c = cnt[b];
        gbase[b] = c ? atomicAdd(&bcur[b], c) : 0;
    }
    __syncthreads();
    for (int i = t; i < B2; i += TPB) cnt[i] = 0;  // reuse as in-block cursor
    __syncthreads();
    for (int i = start + t; i < end; i += TPB) {
        int s = es[i], d = ed[i];
        int b = ((d >> 9) << 3) | (s >> SCH_SHIFT);
        int r = atomicAdd(&cnt[b], 1);
        epk[gbase[b] + r] = (s << 9) | (d & (NPB - 1));
    }
}

// ---- per-bucket degree via LDS hist; dis = rsqrt(deg+1); xs = x * dis ----
__global__ void k_prep(const float* __restrict__ x, const int* __restrict__ bbase,
                       const int* __restrict__ epk,
                       float* __restrict__ dis, float* __restrict__ xs, int n) {
    __shared__ int cnt[NPB];
    int t = threadIdx.x;
    int b = blockIdx.x;
    cnt[t] = 0;
    __syncthreads();
    int e0 = bbase[b << 3], e1 = bbase[(b << 3) + 8];
    for (int e = e0 + t; e < e1; e += TPB)
        atomicAdd(&cnt[epk[e] & (NPB - 1)], 1);
    __syncthreads();
    int v = (b << 9) + t;
    if (v < n) {
        float d = rsqrtf((float)(cnt[t] + 1));
        dis[v] = d;
        const float4* xp = (const float4*)(x + (size_t)v * 12);
        float4 a = xp[0], q = xp[1], c = xp[2];
        float4* op = (float4*)(xs + (size_t)v * 12);
        op[0] = make_float4(a.x * d, a.y * d, a.z * d, a.w * d);
        op[1] = make_float4(q.x * d, q.y * d, q.z * d, q.w * d);
        op[2] = make_float4(c.x * d, c.y * d, c.z * d, c.w * d);
    }
}

// ---- layer1 aggregate in LDS + fused matmuls: h2s = (relu(dis*(agg@W1)+b1) @ W2) * dis ----
__global__ void k_agg1(const float* __restrict__ xs, const float* __restrict__ dis,
                       const int* __restrict__ bbase, const int* __restrict__ epk,
                       const float* __restrict__ W1, const float* __restrict__ b1,
                       const float* __restrict__ W2,
                       float* __restrict__ h2s, int n) {
    __shared__ float acc[NPB * 12];
    __shared__ float sW1[192], sb1[16], sW2[128];
    int t = threadIdx.x;
    int b = blockIdx.x;
    if (t < 192) sW1[t] = W1[t];
    else if (t >= 256 && t < 384) sW2[t - 256] = W2[t - 256];
    else if (t >= 448 && t < 464) sb1[t - 448] = b1[t - 448];
    int base = b << 9;
    int nn = min(NPB, n - base);
    if (t < nn) {
        const float* xp = xs + (size_t)(base + t) * 12;
#pragma unroll
        for (int k = 0; k < 12; k++) acc[t * 12 + k] = xp[k];  // self-loop seed
    }
    __syncthreads();
    int e0 = bbase[b << 3], e1 = bbase[(b << 3) + 8];
    for (int e = e0 + t; e < e1; e += TPB) {
        int p = epk[e];
        int s = p >> 9;
        int r = p & (NPB - 1);
        const float4* pp = (const float4*)(xs + (size_t)s * 12);
        float4 a = pp[0], q = pp[1], c = pp[2];
        float* ar = acc + r * 12;
        atomicAdd(ar + 0, a.x);  atomicAdd(ar + 1, a.y);  atomicAdd(ar + 2, a.z);  atomicAdd(ar + 3, a.w);
        atomicAdd(ar + 4, q.x);  atomicAdd(ar + 5, q.y);  atomicAdd(ar + 6, q.z);  atomicAdd(ar + 7, q.w);
        atomicAdd(ar + 8, c.x);  atomicAdd(ar + 9, c.y);  atomicAdd(ar + 10, c.z); atomicAdd(ar + 11, c.w);
    }
    __syncthreads();
    if (t < nn) {
        int v = base + t;
        float dv = dis[v];
        float aggx[12];
#pragma unroll
        for (int k = 0; k < 12; k++) aggx[k] = acc[t * 12 + k];
        float h1[16];
#pragma unroll
        for (int j = 0; j < 16; j++) {
            float s = 0.f;
#pragma unroll
            for (int k = 0; k < 12; k++) s = fmaf(aggx[k], sW1[k * 16 + j], s);
            h1[j] = fmaxf(fmaf(dv, s, sb1[j]), 0.f);
        }
        float o[8];
#pragma unroll
        for (int j = 0; j < 8; j++) {
            float s = 0.f;
#pragma unroll
            for (int k = 0; k < 16; k++) s = fmaf(h1[k], sW2[k * 8 + j], s);
            o[j] = s * dv;
        }
        float4* hp = (float4*)(h2s + (size_t)v * 8);
        hp[0] = make_float4(o[0], o[1], o[2], o[3]);
        hp[1] = make_float4(o[4], o[5], o[6], o[7]);
    }
}

// ---- layer2 aggregate in LDS + epilogue ----
__global__ void k_agg2(const float* __restrict__ h2s, const float* __restrict__ dis,
                       const int* __restrict__ bbase, const int* __restrict__ epk,
                       const float* __restrict__ b2, float* __restrict__ out, int n) {
    __shared__ float acc[NPB * 8];
    __shared__ float sb2[8];
    int t = threadIdx.x;
    int b = blockIdx.x;
    if (t < 8) sb2[t] = b2[t];
    int base = b << 9;
    int nn = min(NPB, n - base);
    if (t < nn) {
        const float4* hp = (const float4*)(h2s + (size_t)(base + t) * 8);
        float4 a = hp[0], c = hp[1];
        float* ar = acc + t * 8;
        ar[0] = a.x; ar[1] = a.y; ar[2] = a.z; ar[3] = a.w;
        ar[4] = c.x; ar[5] = c.y; ar[6] = c.z; ar[7] = c.w;
    }
    __syncthreads();
    int e0 = bbase[b << 3], e1 = bbase[(b << 3) + 8];
    for (int e = e0 + t; e < e1; e += TPB) {
        int p = epk[e];
        int s = p >> 9;
        int r = p & (NPB - 1);
        const float4* pp = (const float4*)(h2s + (size_t)s * 8);
        float4 a = pp[0], c = pp[1];
        float* ar = acc + r * 8;
        atomicAdd(ar + 0, a.x); atomicAdd(ar + 1, a.y); atomicAdd(ar + 2, a.z); atomicAdd(ar + 3, a.w);
        atomicAdd(ar + 4, c.x); atomicAdd(ar + 5, c.y); atomicAdd(ar + 6, c.z); atomicAdd(ar + 7, c.w);
    }
    __syncthreads();
    if (t < nn) {
        int v = base + t;
        float dv = dis[v];
        float* ar = acc + t * 8;
        float4* op = (float4*)(out + (size_t)v * 8);
        op[0] = make_float4(fmaf(dv, ar[0], sb2[0]), fmaf(dv, ar[1], sb2[1]),
                            fmaf(dv, ar[2], sb2[2]), fmaf(dv, ar[3], sb2[3]));
        op[1] = make_float4(fmaf(dv, ar[4], sb2[4]), fmaf(dv, ar[5], sb2[5]),
                            fmaf(dv, ar[6], sb2[6]), fmaf(dv, ar[7], sb2[7]));
    }
}

extern "C" void kernel_launch(void* const* d_in, const int* in_sizes, int n_in,
                              void* d_out, int out_size, void* d_ws, size_t ws_size,
                              hipStream_t stream) {
    const float* x  = (const float*)d_in[0];
    const int*   ei = (const int*)d_in[1];
    const float* W1 = (const float*)d_in[2];
    const float* b1 = (const float*)d_in[3];
    const float* W2 = (const float*)d_in[4];
    const float* b2 = (const float*)d_in[5];
    float* out = (float*)d_out;

    int n = in_sizes[0] / 12;
    int E = in_sizes[1] / 2;
    const int* es = ei;       // edge_index[0] = src
    const int* ed = ei + E;   // edge_index[1] = dst

    int B = (n + NPB - 1) >> 9;   // dst buckets (977 for n=500K)
    int B2 = B << 3;              // (bucket, src-chunk) bins, <= 8192

    // workspace layout (byte offsets):
    // gcnt @0 (32KB) | bbase @32KB (36KB, B2+1) | bcur @68KB (32KB) | dis @100KB (4n)
    // xs = dis+n (48n B) | h2s = xs+12n (32n B) | epk = h2s+8n (4E B)  => ~106 MB
    char* wp = (char*)d_ws;
    int* gcnt  = (int*)wp;
    int* bbase = (int*)(wp + (32 << 10));
    int* bcur  = (int*)(wp + (68 << 10));
    float* dis = (float*)(wp + (100 << 10));
    size_t nAl = ((size_t)n + 3) & ~(size_t)3;
    float* xs  = dis + nAl;
    float* h2s = xs + 12 * nAl;
    int* epk   = (int*)(h2s + 8 * nAl);

    int nchunks = (E + CH - 1) / CH;

    k_zero<<<(B2 + 255) / 256, 256, 0, stream>>>(gcnt, B2);
    k_count<<<nchunks, TPB, 0, stream>>>(es, ed, gcnt, E, B2);
    k_scan<<<1, 1024, 0, stream>>>(gcnt, bbase, bcur, B2, E);
    k_scatter<<<nchunks, TPB, 0, stream>>>(es, ed, bcur, epk, E, B2);
    k_prep<<<B, TPB, 0, stream>>>(x, bbase, epk, dis, xs, n);
    k_agg1<<<B, TPB, 0, stream>>>(xs, dis, bbase, epk, W1, b1, W2, h2s, n);
    k_agg2<<<B, TPB, 0, stream>>>(h2s, dis, bbase, epk, b2, out, n);
}